// Round 7
// baseline (120.467 us; speedup 1.0000x reference)
//
#include <hip/hip_runtime.h>
#include <hip/hip_fp16.h>

typedef _Float16 f16;
typedef __fp16 hf16x2 __attribute__((ext_vector_type(2)));
typedef _Float16 f16x8 __attribute__((ext_vector_type(8)));
typedef _Float16 f16x4v __attribute__((ext_vector_type(4)));
typedef float f32x4 __attribute__((ext_vector_type(4)));

#define B_ 2
#define S_ 2048
#define E_ 1024
#define H_ 16
#define DH_ 64

__device__ __forceinline__ f32x4 mfma16(f16x8 a, f16x8 b, f32x4 c) {
    return __builtin_amdgcn_mfma_f32_16x16x32_f16(a, b, c, 0, 0, 0);
}

__device__ __forceinline__ f32x4 vmax4(f32x4 a, f32x4 b) {
    f32x4 r;
    r[0] = fmaxf(a[0], b[0]); r[1] = fmaxf(a[1], b[1]);
    r[2] = fmaxf(a[2], b[2]); r[3] = fmaxf(a[3], b[3]);
    return r;
}

__device__ __forceinline__ f16x8 cvt8(const float* p) {
    float4 v0 = *(const float4*)p;
    float4 v1 = *(const float4*)(p + 4);
    f16x8 r;
    r[0] = (f16)v0.x; r[1] = (f16)v0.y; r[2] = (f16)v0.z; r[3] = (f16)v0.w;
    r[4] = (f16)v1.x; r[5] = (f16)v1.y; r[6] = (f16)v1.z; r[7] = (f16)v1.w;
    return r;
}

// ---------------------------------------------------------------------------
// Kernel 1: per-head projections + Wo f32->f16 convert (merged; independent
// work, one launch). Blocks [0,3072): proj. Blocks [3072,4096): cvt.
// ---------------------------------------------------------------------------
__global__ __launch_bounds__(256) void proj_cvt_kernel(
    const float* __restrict__ q_in, const float* __restrict__ k_in,
    const float* __restrict__ v_in,
    const float* __restrict__ Wq, const float* __restrict__ Wk,
    const float* __restrict__ Wv, const float* __restrict__ Wo,
    f16* __restrict__ Qg, f16* __restrict__ Kg, f16* __restrict__ Vt,
    f16* __restrict__ WoH)
{
    int tid = threadIdx.x;
    int bx = blockIdx.x;
    if (bx >= 3072) {
        int i = (bx - 3072) * 256 + tid;
        float4 v = *(const float4*)(Wo + (size_t)i * 4);
        f16x4v o;
        o[0] = (f16)v.x; o[1] = (f16)v.y; o[2] = (f16)v.z; o[3] = (f16)v.w;
        *(f16x4v*)(WoH + (size_t)i * 4) = o;
        return;
    }

    int lane = tid & 63, wv = tid >> 6;
    int wid = bx * 4 + wv;
    int proj = wid >> 12;
    int r = wid & 4095;
    int bh = r >> 7;
    int stile = r & 127;
    int sbase = stile * 16;
    int h = bh & 15;
    int b = bh >> 4;
    int c = lane & 15, g = lane >> 4;

    const float* x; const float* W;
    if (proj == 0)      { x = q_in; W = Wq; }
    else if (proj == 1) { x = k_in; W = Wk; }
    else                { x = v_in; W = Wv; }

    const float* xrow = x + (((size_t)(b * S_ + sbase + c) * H_ + h) << 6);
    f16x8 a0 = cvt8(xrow + g * 8);
    f16x8 a1 = cvt8(xrow + 32 + g * 8);

    f32x4 acc[4] = {};
#pragma unroll
    for (int nt = 0; nt < 4; ++nt) {
        const float* wrow = W + ((nt * 16 + c) << 6);
        f16x8 b0 = cvt8(wrow + g * 8);
        f16x8 b1 = cvt8(wrow + 32 + g * 8);
        acc[nt] = mfma16(a0, b0, acc[nt]);
        acc[nt] = mfma16(a1, b1, acc[nt]);
    }

    if (proj < 2) {
        f16* out = (proj == 0) ? Qg : Kg;
#pragma unroll
        for (int nt = 0; nt < 4; ++nt)
#pragma unroll
            for (int j = 0; j < 4; ++j) {
                int s = sbase + g * 4 + j;
                out[((size_t)bh * S_ + s) * DH_ + nt * 16 + c] = (f16)acc[nt][j];
            }
    } else {
#pragma unroll
        for (int nt = 0; nt < 4; ++nt) {
            f16x4v pk;
            pk[0] = (f16)acc[nt][0]; pk[1] = (f16)acc[nt][1];
            pk[2] = (f16)acc[nt][2]; pk[3] = (f16)acc[nt][3];
            *(f16x4v*)&Vt[((size_t)bh * DH_ + nt * 16 + c) * S_ + sbase + g * 4] = pk;
        }
    }
}

// ---------------------------------------------------------------------------
// Kernel 2: flash attention. 256 thr = 4 waves x 16 q-rows (block = 64 q).
// KT=64 keys/iter, compile-time double-buffer, 1 barrier/iter. LDS 40 KB ->
// 4 blocks/CU (4 independent barrier domains per CU for latency overlap).
// XCD-swizzled grid (4 bh per XCD -> 2 MB K/V L2-resident).
// Swapped QK^T -> per-lane softmax, defer-max, per-lane l partials,
// pkrtz-packed P via per-wave swizzled LDS slab.
// ---------------------------------------------------------------------------
#define C1_ 0.18033688011112042f   // log2(e)/sqrt(64)

__global__ __launch_bounds__(256, 4) void attn_kernel(
    const f16* __restrict__ Qg, const f16* __restrict__ Kg,
    const f16* __restrict__ Vt, f16* __restrict__ ctx)
{
    __shared__ __align__(16) f16 Kl[2][64 * 64];   // [key][d], swizzled
    __shared__ __align__(16) f16 Vl[2][64 * 64];   // [d][key], swizzled
    __shared__ __align__(16) f16 Pl[4][16 * 64];   // per-wave [q][key]

    int tid = threadIdx.x, lane = tid & 63, wv = tid >> 6;
    int bid = blockIdx.x;
    int sb = (bid & 7) * 128 + (bid >> 3);     // XCD-contiguous: bh-major
    int bh = sb >> 5, qt = sb & 31;
    int b = bh >> 4, h = bh & 15;
    int qbase = qt * 64 + wv * 16;
    int c = lane & 15, g = lane >> 4;
    int swz = (c & 7) << 3;

    const f16* Qh = Qg + (size_t)bh * S_ * DH_;
    const f16* Kh = Kg + (size_t)bh * S_ * DH_;
    const f16* Vh = Vt + (size_t)bh * DH_ * S_;

    // staging: K tile 64x64 f16 = 512 16B slots, 2 per thread; same for V.
    int s0 = tid, s1 = tid + 256;
    int kr0 = s0 >> 3, kc0 = s0 & 7, kr1 = s1 >> 3, kc1 = s1 & 7;
    int kd0 = kr0 * 64 + ((kc0 * 8) ^ ((kr0 & 7) << 3));
    int kd1 = kr1 * 64 + ((kc1 * 8) ^ ((kr1 & 7) << 3));
    const f16* ksp0 = Kh + kr0 * 64 + kc0 * 8;
    const f16* ksp1 = Kh + kr1 * 64 + kc1 * 8;
    const f16* vsp0 = Vh + kr0 * S_ + kc0 * 8;
    const f16* vsp1 = Vh + kr1 * S_ + kc1 * 8;

    // Q fragments (B-operand): lane holds Q[q=qbase+c][d=32*hh+8g..]
    f16x8 qf[2];
#pragma unroll
    for (int hh = 0; hh < 2; ++hh)
        qf[hh] = *(const f16x8*)(Qh + (size_t)(qbase + c) * DH_ + hh * 32 + g * 8);

    float m2 = -1e30f;
    f32x4 lrv = {};
    f32x4 accO[4] = {};
    f16x8 kreg0, kreg1, vreg0, vreg1;

    // prologue: stage tile 0
    kreg0 = *(const f16x8*)ksp0; kreg1 = *(const f16x8*)ksp1;
    vreg0 = *(const f16x8*)vsp0; vreg1 = *(const f16x8*)vsp1;
    *(f16x8*)&Kl[0][kd0] = kreg0; *(f16x8*)&Kl[0][kd1] = kreg1;
    *(f16x8*)&Vl[0][kd0] = vreg0; *(f16x8*)&Vl[0][kd1] = vreg1;
    __syncthreads();

#define ATTN_STEP(CUR, T, STAGE)                                               \
    do {                                                                       \
        if (STAGE) {                                                           \
            int ko = ((T) + 1) * 64 * 64, vo = ((T) + 1) * 64;                 \
            kreg0 = *(const f16x8*)(ksp0 + ko);                                \
            kreg1 = *(const f16x8*)(ksp1 + ko);                                \
            vreg0 = *(const f16x8*)(vsp0 + vo);                                \
            vreg1 = *(const f16x8*)(vsp1 + vo);                                \
        }                                                                      \
        f32x4 accS[4] = {};                                                    \
        __builtin_amdgcn_s_setprio(1);                                         \
        _Pragma("unroll")                                                      \
        for (int ks = 0; ks < 4; ++ks) {                                       \
            int krow = (ks * 16 + c) * 64;                                     \
            f16x8 k0 = *(const f16x8*)&Kl[CUR][krow + ((8 * g) ^ swz)];        \
            f16x8 k1 = *(const f16x8*)&Kl[CUR][krow + ((32 + 8 * g) ^ swz)];   \
            accS[ks] = mfma16(k0, qf[0], accS[ks]);                            \
            accS[ks] = mfma16(k1, qf[1], accS[ks]);                            \
        }                                                                      \
        __builtin_amdgcn_s_setprio(0);                                         \
        f32x4 mx4 = vmax4(vmax4(accS[0], accS[1]), vmax4(accS[2], accS[3]));   \
        float rmax = fmaxf(fmaxf(mx4[0], mx4[1]), fmaxf(mx4[2], mx4[3]));      \
        if (!__all(fmaf(rmax, C1_, -m2) <= 8.f)) {                             \
            float mx = fmaxf(rmax, __shfl_xor(rmax, 16));                      \
            mx = fmaxf(mx, __shfl_xor(mx, 32));                                \
            float mn = fmaxf(m2, mx * C1_);                                    \
            float al = exp2f(m2 - mn);                                         \
            m2 = mn;                                                           \
            _Pragma("unroll")                                                  \
            for (int j = 0; j < 4; ++j) lrv[j] *= al;                          \
            _Pragma("unroll")                                                  \
            for (int j = 0; j < 4; ++j) {                                      \
                float aj = __shfl(al, 4 * g + j);                              \
                _Pragma("unroll")                                              \
                for (int nt = 0; nt < 4; ++nt) accO[nt][j] *= aj;              \
            }                                                                  \
        }                                                                      \
        _Pragma("unroll")                                                      \
        for (int ks = 0; ks < 4; ++ks) {                                       \
            f32x4 e;                                                           \
            _Pragma("unroll")                                                  \
            for (int j = 0; j < 4; ++j)                                        \
                e[j] = exp2f(fmaf(accS[ks][j], C1_, -m2));                     \
            lrv += e;                                                          \
            hf16x2 lo = __builtin_amdgcn_cvt_pkrtz(e[0], e[1]);                \
            hf16x2 hi = __builtin_amdgcn_cvt_pkrtz(e[2], e[3]);                \
            uint2 w;                                                           \
            w.x = __builtin_bit_cast(unsigned, lo);                            \
            w.y = __builtin_bit_cast(unsigned, hi);                            \
            *(uint2*)&Pl[wv][c * 64 + ((16 * ks + 4 * g) ^ swz)] = w;          \
        }                                                                      \
        __builtin_amdgcn_s_setprio(1);                                         \
        _Pragma("unroll")                                                      \
        for (int kh = 0; kh < 2; ++kh) {                                       \
            f16x8 pa = *(const f16x8*)&Pl[wv][c * 64 + ((32 * kh + 8 * g) ^ swz)];\
            _Pragma("unroll")                                                  \
            for (int nt = 0; nt < 4; ++nt) {                                   \
                f16x8 vb = *(const f16x8*)&Vl[CUR][(nt * 16 + c) * 64          \
                                + ((32 * kh + 8 * g) ^ swz)];                  \
                accO[nt] = mfma16(pa, vb, accO[nt]);                           \
            }                                                                  \
        }                                                                      \
        __builtin_amdgcn_s_setprio(0);                                         \
        if (STAGE) {                                                           \
            int nb = (CUR) ^ 1;                                                \
            *(f16x8*)&Kl[nb][kd0] = kreg0; *(f16x8*)&Kl[nb][kd1] = kreg1;      \
            *(f16x8*)&Vl[nb][kd0] = vreg0; *(f16x8*)&Vl[nb][kd1] = vreg1;      \
            __syncthreads();                                                   \
        }                                                                      \
    } while (0)

#pragma unroll 1
    for (int kt = 0; kt < 30; kt += 2) {
        ATTN_STEP(0, kt, 1);
        ATTN_STEP(1, kt + 1, 1);
    }
    ATTN_STEP(0, 30, 1);
    ATTN_STEP(1, 31, 0);
#undef ATTN_STEP

    // epilogue: reduce l across g, divide, write ctx
    float lr = (lrv[0] + lrv[1]) + (lrv[2] + lrv[3]);
    lr += __shfl_xor(lr, 16);
    lr += __shfl_xor(lr, 32);
    float inv = 1.f / lr;
#pragma unroll
    for (int j = 0; j < 4; ++j) {
        float lj = __shfl(inv, 4 * g + j);
        int s = qbase + 4 * g + j;
#pragma unroll
        for (int nt = 0; nt < 4; ++nt)
            ctx[((size_t)b * S_ + s) * E_ + h * DH_ + nt * 16 + c] =
                (f16)(accO[nt][j] * lj);
    }
}

// ---------------------------------------------------------------------------
// Kernel 3: out = ctx @ Wo^T + bo. 128x64 tiles, BK=64, swizzled LDS,
// compile-time double-buffer, f16 B (pre-converted Wo), XCD-swizzled grid.
// ---------------------------------------------------------------------------
__global__ __launch_bounds__(256) void gemm_out(
    const f16* __restrict__ A,    // ctx [4096][1024] f16
    const f16* __restrict__ Bw,   // Wo f16 [1024][1024]
    const float* __restrict__ bo,
    float* __restrict__ out)      // [4096][1024] fp32
{
    __shared__ __align__(16) f16 Al[2][128 * 64];
    __shared__ __align__(16) f16 Bl[2][64 * 64];

    int tid = threadIdx.x, lane = tid & 63, wv = tid >> 6;
    int bid = blockIdx.x;
    int sb = (bid & 7) * 64 + (bid >> 3);   // XCD-contiguous: nbase-major
    int mbase = (sb & 31) * 128, nbase = (sb >> 5) * 64;
    int c = lane & 15, g = lane >> 4;
    int wr = wv >> 1, wc = wv & 1;
    int swz = (c & 7) << 3;

    int adst[4]; const f16* asrc[4];
#pragma unroll
    for (int i = 0; i < 4; ++i) {
        int slot = tid + i * 256;
        int row = slot >> 3, cc = slot & 7;
        adst[i] = row * 64 + ((cc * 8) ^ ((row & 7) << 3));
        asrc[i] = A + (size_t)(mbase + row) * 1024 + cc * 8;
    }
    int bdst[2]; const f16* bsrc[2];
#pragma unroll
    for (int i = 0; i < 2; ++i) {
        int slot = tid + i * 256;
        int row = slot >> 3, cc = slot & 7;
        bdst[i] = row * 64 + ((cc * 8) ^ ((row & 7) << 3));
        bsrc[i] = Bw + (size_t)(nbase + row) * 1024 + cc * 8;
    }

    f32x4 acc[4][2] = {};
    f16x8 areg[4], breg[2];

    // prologue: stage K-step 0
#pragma unroll
    for (int i = 0; i < 4; ++i) areg[i] = *(const f16x8*)asrc[i];
#pragma unroll
    for (int i = 0; i < 2; ++i) breg[i] = *(const f16x8*)bsrc[i];
#pragma unroll
    for (int i = 0; i < 4; ++i) *(f16x8*)&Al[0][adst[i]] = areg[i];
#pragma unroll
    for (int i = 0; i < 2; ++i) *(f16x8*)&Bl[0][bdst[i]] = breg[i];
    __syncthreads();

#define GEMM_STEP(CUR, T, STAGE)                                               \
    do {                                                                       \
        if (STAGE) {                                                           \
            _Pragma("unroll")                                                  \
            for (int i = 0; i < 4; ++i)                                        \
                areg[i] = *(const f16x8*)(asrc[i] + ((T) + 1) * 64);           \
            _Pragma("unroll")                                                  \
            for (int i = 0; i < 2; ++i)                                        \
                breg[i] = *(const f16x8*)(bsrc[i] + ((T) + 1) * 64);           \
        }                                                                      \
        __builtin_amdgcn_s_setprio(1);                                         \
        _Pragma("unroll")                                                      \
        for (int kk = 0; kk < 2; ++kk) {                                       \
            f16x8 af[4], bf[2];                                                \
            _Pragma("unroll")                                                  \
            for (int mi = 0; mi < 4; ++mi)                                     \
                af[mi] = *(const f16x8*)&Al[CUR][(wr * 64 + mi * 16 + c) * 64  \
                                               + ((32 * kk + 8 * g) ^ swz)];   \
            _Pragma("unroll")                                                  \
            for (int ni = 0; ni < 2; ++ni)                                     \
                bf[ni] = *(const f16x8*)&Bl[CUR][(wc * 32 + ni * 16 + c) * 64  \
                                               + ((32 * kk + 8 * g) ^ swz)];   \
            _Pragma("unroll")                                                  \
            for (int mi = 0; mi < 4; ++mi)                                     \
                _Pragma("unroll")                                              \
                for (int ni = 0; ni < 2; ++ni)                                 \
                    acc[mi][ni] = mfma16(af[mi], bf[ni], acc[mi][ni]);         \
        }                                                                      \
        __builtin_amdgcn_s_setprio(0);                                         \
        if (STAGE) {                                                           \
            int nb = (CUR) ^ 1;                                                \
            _Pragma("unroll")                                                  \
            for (int i = 0; i < 4; ++i) *(f16x8*)&Al[nb][adst[i]] = areg[i];   \
            _Pragma("unroll")                                                  \
            for (int i = 0; i < 2; ++i) *(f16x8*)&Bl[nb][bdst[i]] = breg[i];   \
            __syncthreads();                                                   \
        }                                                                      \
    } while (0)

#pragma unroll 1
    for (int ks = 0; ks < 14; ks += 2) {
        GEMM_STEP(0, ks, 1);
        GEMM_STEP(1, ks + 1, 1);
    }
    GEMM_STEP(0, 14, 1);
    GEMM_STEP(1, 15, 0);
#undef GEMM_STEP

    // epilogue: + bias, fp32 store
#pragma unroll
    for (int ni = 0; ni < 2; ++ni) {
        float bias = bo[nbase + wc * 32 + ni * 16 + c];
#pragma unroll
        for (int mi = 0; mi < 4; ++mi)
#pragma unroll
            for (int j = 0; j < 4; ++j) {
                int m = mbase + wr * 64 + mi * 16 + g * 4 + j;
                out[(size_t)m * 1024 + nbase + wc * 32 + ni * 16 + c] =
                    acc[mi][ni][j] + bias;
            }
    }
}

extern "C" void kernel_launch(void* const* d_in, const int* in_sizes, int n_in,
                              void* d_out, int out_size, void* d_ws, size_t ws_size,
                              hipStream_t stream)
{
    const float* k_in = (const float*)d_in[0];
    const float* q_in = (const float*)d_in[1];
    const float* v_in = (const float*)d_in[2];
    const float* Wq   = (const float*)d_in[3];
    const float* Wk   = (const float*)d_in[4];
    const float* Wv   = (const float*)d_in[5];
    const float* Wo   = (const float*)d_in[6];
    const float* bo   = (const float*)d_in[7];
    float* out = (float*)d_out;

    char* ws = (char*)d_ws;
    f16* Qg  = (f16*)(ws);
    f16* Kg  = (f16*)(ws + (8u << 20));
    f16* Vt  = (f16*)(ws + (16u << 20));
    f16* ctx = (f16*)(ws + (24u << 20));
    f16* WoH = (f16*)(ws + (32u << 20));

    proj_cvt_kernel<<<dim3(4096), dim3(256), 0, stream>>>(
        q_in, k_in, v_in, Wq, Wk, Wv, Wo, Qg, Kg, Vt, WoH);
    attn_kernel<<<dim3(1024), dim3(256), 0, stream>>>(Qg, Kg, Vt, ctx);
    gemm_out<<<dim3(512), dim3(256), 0, stream>>>(ctx, WoH, bo, out);
}

// Round 8
// 118.636 us; speedup vs baseline: 1.0154x; 1.0154x over previous
//
#include <hip/hip_runtime.h>
#include <hip/hip_fp16.h>

typedef _Float16 f16;
typedef __fp16 hf16x2 __attribute__((ext_vector_type(2)));
typedef _Float16 f16x8 __attribute__((ext_vector_type(8)));
typedef _Float16 f16x4v __attribute__((ext_vector_type(4)));
typedef float f32x4 __attribute__((ext_vector_type(4)));
typedef float f32x16 __attribute__((ext_vector_type(16)));

#define B_ 2
#define S_ 2048
#define E_ 1024
#define H_ 16
#define DH_ 64

__device__ __forceinline__ f32x4 mfma16(f16x8 a, f16x8 b, f32x4 c) {
    return __builtin_amdgcn_mfma_f32_16x16x32_f16(a, b, c, 0, 0, 0);
}
__device__ __forceinline__ f32x16 mfma32(f16x8 a, f16x8 b, f32x16 c) {
    return __builtin_amdgcn_mfma_f32_32x32x16_f16(a, b, c, 0, 0, 0);
}

__device__ __forceinline__ f16x8 cvt8(const float* p) {
    float4 v0 = *(const float4*)p;
    float4 v1 = *(const float4*)(p + 4);
    f16x8 r;
    r[0] = (f16)v0.x; r[1] = (f16)v0.y; r[2] = (f16)v0.z; r[3] = (f16)v0.w;
    r[4] = (f16)v1.x; r[5] = (f16)v1.y; r[6] = (f16)v1.z; r[7] = (f16)v1.w;
    return r;
}

// ---------------------------------------------------------------------------
// Kernel 1: per-head projections + Wo f32->f16 convert (merged).
// ---------------------------------------------------------------------------
__global__ __launch_bounds__(256) void proj_cvt_kernel(
    const float* __restrict__ q_in, const float* __restrict__ k_in,
    const float* __restrict__ v_in,
    const float* __restrict__ Wq, const float* __restrict__ Wk,
    const float* __restrict__ Wv, const float* __restrict__ Wo,
    f16* __restrict__ Qg, f16* __restrict__ Kg, f16* __restrict__ Vt,
    f16* __restrict__ WoH)
{
    int tid = threadIdx.x;
    int bx = blockIdx.x;
    if (bx >= 3072) {
        int i = (bx - 3072) * 256 + tid;
        float4 v = *(const float4*)(Wo + (size_t)i * 4);
        f16x4v o;
        o[0] = (f16)v.x; o[1] = (f16)v.y; o[2] = (f16)v.z; o[3] = (f16)v.w;
        *(f16x4v*)(WoH + (size_t)i * 4) = o;
        return;
    }

    int lane = tid & 63, wv = tid >> 6;
    int wid = bx * 4 + wv;
    int proj = wid >> 12;
    int r = wid & 4095;
    int bh = r >> 7;
    int stile = r & 127;
    int sbase = stile * 16;
    int h = bh & 15;
    int b = bh >> 4;
    int c = lane & 15, g = lane >> 4;

    const float* x; const float* W;
    if (proj == 0)      { x = q_in; W = Wq; }
    else if (proj == 1) { x = k_in; W = Wk; }
    else                { x = v_in; W = Wv; }

    const float* xrow = x + (((size_t)(b * S_ + sbase + c) * H_ + h) << 6);
    f16x8 a0 = cvt8(xrow + g * 8);
    f16x8 a1 = cvt8(xrow + 32 + g * 8);

    f32x4 acc[4] = {};
#pragma unroll
    for (int nt = 0; nt < 4; ++nt) {
        const float* wrow = W + ((nt * 16 + c) << 6);
        f16x8 b0 = cvt8(wrow + g * 8);
        f16x8 b1 = cvt8(wrow + 32 + g * 8);
        acc[nt] = mfma16(a0, b0, acc[nt]);
        acc[nt] = mfma16(a1, b1, acc[nt]);
    }

    if (proj < 2) {
        f16* out = (proj == 0) ? Qg : Kg;
#pragma unroll
        for (int nt = 0; nt < 4; ++nt)
#pragma unroll
            for (int j = 0; j < 4; ++j) {
                int s = sbase + g * 4 + j;
                out[((size_t)bh * S_ + s) * DH_ + nt * 16 + c] = (f16)acc[nt][j];
            }
    } else {
#pragma unroll
        for (int nt = 0; nt < 4; ++nt) {
            f16x4v pk;
            pk[0] = (f16)acc[nt][0]; pk[1] = (f16)acc[nt][1];
            pk[2] = (f16)acc[nt][2]; pk[3] = (f16)acc[nt][3];
            *(f16x4v*)&Vt[((size_t)bh * DH_ + nt * 16 + c) * S_ + sbase + g * 4] = pk;
        }
    }
}

// ---------------------------------------------------------------------------
// Kernel 2: flash attention, 32x32 MFMA, in-register P.
// 256 thr = 4 waves x 32 q-rows (block = 128 q). KVBLK=64, dbuf, 1 barrier.
// LDS [32][128] pitch, col ^= (row&15)<<3 swizzle. Swapped QK^T:
//   accS: q = lane&31, key(reg r) = (r&3)+8*(r>>2)+4*(lane>>5) (+32*sub)
//   -> softmax fully per-lane (+1 shfl_xor(32) for the cross-half max/sum)
//   -> exp2 -> cvt_pkrtz words -> shfl_xor(32)+select assembles PV A-frags
//      in registers (no P LDS slab at all).
// ---------------------------------------------------------------------------
#define C1_ 0.18033688011112042f   // log2(e)/sqrt(64)

__global__ __launch_bounds__(256, 2) void attn_kernel(
    const f16* __restrict__ Qg, const f16* __restrict__ Kg,
    const f16* __restrict__ Vt, f16* __restrict__ ctx)
{
    // [0,8192): K dbuf (two 32x128 f16 tiles), [8192,16384): V dbuf
    __shared__ __align__(16) f16 lds[16384];

    int tid = threadIdx.x, lane = tid & 63, wv = tid >> 6;
    int bid = blockIdx.x;
    int sb = (bid & 7) * 64 + (bid >> 3);    // XCD-contiguous: bh-major
    int bh = sb >> 4, qt = sb & 15;
    int b = bh >> 4, h = bh & 15;
    int qbase = qt * 128 + wv * 32;
    int q32 = lane & 31, hh = lane >> 5;
    bool isLo = (hh == 0);

    const f16* Qh = Qg + (size_t)bh * S_ * DH_;
    const f16* Kh = Kg + (size_t)bh * S_ * DH_;
    const f16* Vh = Vt + (size_t)bh * DH_ * S_;

    // read addresses: cr[4a+s] for tile half a (K: key-half / V: d-half) and
    // 16-col slice s. row = q32, pitch 128, col ^= (row&15)<<3.
    int swzr = (q32 & 15) << 3;
    int cr[8];
#pragma unroll
    for (int a = 0; a < 2; ++a)
#pragma unroll
        for (int s = 0; s < 4; ++s)
            cr[4 * a + s] = q32 * 128 + ((a * 64 + 16 * s + 8 * hh) ^ swzr);

    // staging: 64x64 f16 tile = 512 16B slots; 256 threads x 2 slots.
    // element (e, d-chunk cc): row = e&31, col = (e>>5)*64 + cc*8 (^ swz).
    int s0 = tid, s1 = tid + 256;
    int e0 = s0 >> 3, c0 = s0 & 7, e1 = s1 >> 3, c1 = s1 & 7;
    int wd0 = (e0 & 31) * 128 + ((((e0 >> 5) * 64) + c0 * 8) ^ (((e0 & 31) & 15) << 3));
    int wd1 = (e1 & 31) * 128 + ((((e1 >> 5) * 64) + c1 * 8) ^ (((e1 & 31) & 15) << 3));
    const f16* ksp0 = Kh + e0 * 64 + c0 * 8;
    const f16* ksp1 = Kh + e1 * 64 + c1 * 8;
    const f16* vsp0 = Vh + (size_t)e0 * S_ + c0 * 8;
    const f16* vsp1 = Vh + (size_t)e1 * S_ + c1 * 8;

    // Q fragments (B-operand): lane holds Q[q=qbase+q32][d = 16s + 8hh + i]
    f16x8 qf[4];
#pragma unroll
    for (int s = 0; s < 4; ++s)
        qf[s] = *(const f16x8*)(Qh + (size_t)(qbase + q32) * DH_ + 16 * s + 8 * hh);

    float m2 = -1e30f, lrv = 0.f;
    f32x16 accO0 = {}, accO1 = {};
    f16x8 kreg0, kreg1, vreg0, vreg1;

    // prologue: stage tile 0
    kreg0 = *(const f16x8*)ksp0; kreg1 = *(const f16x8*)ksp1;
    vreg0 = *(const f16x8*)vsp0; vreg1 = *(const f16x8*)vsp1;
    *(f16x8*)&lds[wd0] = kreg0; *(f16x8*)&lds[wd1] = kreg1;
    *(f16x8*)&lds[8192 + wd0] = vreg0; *(f16x8*)&lds[8192 + wd1] = vreg1;
    __syncthreads();

#define ATTN_SUB(CUR, SUBI)                                                    \
    do {                                                                       \
        f32x16 accS = {};                                                      \
        __builtin_amdgcn_s_setprio(1);                                         \
        _Pragma("unroll")                                                      \
        for (int s = 0; s < 4; ++s) {                                          \
            f16x8 kf = *(const f16x8*)&lds[(CUR) * 4096 + cr[4 * (SUBI) + s]]; \
            accS = mfma32(kf, qf[s], accS);                                    \
        }                                                                      \
        __builtin_amdgcn_s_setprio(0);                                         \
        float rmax = accS[0];                                                  \
        _Pragma("unroll")                                                      \
        for (int r = 1; r < 16; ++r) rmax = fmaxf(rmax, accS[r]);              \
        rmax = fmaxf(rmax, __shfl_xor(rmax, 32));                              \
        if (!__all(fmaf(rmax, C1_, -m2) <= 8.f)) {                             \
            float mn = fmaxf(m2, rmax * C1_);                                  \
            float al = exp2f(m2 - mn);                                         \
            m2 = mn; lrv *= al;                                                \
            _Pragma("unroll")                                                  \
            for (int r = 0; r < 16; ++r) {                                     \
                float aj = __shfl(al, ((r & 3) + 8 * (r >> 2)) + 4 * hh);      \
                accO0[r] *= aj; accO1[r] *= aj;                                \
            }                                                                  \
        }                                                                      \
        unsigned w[8];                                                         \
        _Pragma("unroll")                                                      \
        for (int j = 0; j < 8; ++j) {                                          \
            float ea = exp2f(fmaf(accS[2 * j], C1_, -m2));                     \
            float eb = exp2f(fmaf(accS[2 * j + 1], C1_, -m2));                 \
            lrv += ea + eb;                                                    \
            hf16x2 pk = __builtin_amdgcn_cvt_pkrtz(ea, eb);                    \
            w[j] = __builtin_bit_cast(unsigned, pk);                           \
        }                                                                      \
        _Pragma("unroll")                                                      \
        for (int s2 = 0; s2 < 2; ++s2) {                                       \
            unsigned b0 = w[4 * s2 + 0], b1 = w[4 * s2 + 1];                   \
            unsigned b2 = w[4 * s2 + 2], b3 = w[4 * s2 + 3];                   \
            unsigned x0 = (unsigned)__shfl_xor((int)b0, 32);                   \
            unsigned x1 = (unsigned)__shfl_xor((int)b1, 32);                   \
            unsigned x2 = (unsigned)__shfl_xor((int)b2, 32);                   \
            unsigned x3 = (unsigned)__shfl_xor((int)b3, 32);                   \
            uint4 au;                                                          \
            au.x = isLo ? b0 : x2;                                             \
            au.y = isLo ? b1 : x3;                                             \
            au.z = isLo ? x0 : b2;                                             \
            au.w = isLo ? x1 : b3;                                             \
            f16x8 pa = __builtin_bit_cast(f16x8, au);                          \
            __builtin_amdgcn_s_setprio(1);                                     \
            {                                                                  \
                f16x8 vb = *(const f16x8*)&lds[8192 + (CUR) * 4096             \
                                               + cr[(SUBI) * 2 + s2]];         \
                accO0 = mfma32(pa, vb, accO0);                                 \
            }                                                                  \
            {                                                                  \
                f16x8 vb = *(const f16x8*)&lds[8192 + (CUR) * 4096             \
                                               + cr[4 + (SUBI) * 2 + s2]];     \
                accO1 = mfma32(pa, vb, accO1);                                 \
            }                                                                  \
            __builtin_amdgcn_s_setprio(0);                                     \
        }                                                                      \
    } while (0)

#define ATTN_STEP(CUR, T, STAGE)                                               \
    do {                                                                       \
        if (STAGE) {                                                           \
            kreg0 = *(const f16x8*)(ksp0 + ((T) + 1) * 4096);                  \
            kreg1 = *(const f16x8*)(ksp1 + ((T) + 1) * 4096);                  \
            vreg0 = *(const f16x8*)(vsp0 + ((T) + 1) * 64);                    \
            vreg1 = *(const f16x8*)(vsp1 + ((T) + 1) * 64);                    \
        }                                                                      \
        ATTN_SUB(CUR, 0);                                                      \
        ATTN_SUB(CUR, 1);                                                      \
        if (STAGE) {                                                           \
            int nb = (CUR) ^ 1;                                                \
            *(f16x8*)&lds[nb * 4096 + wd0] = kreg0;                            \
            *(f16x8*)&lds[nb * 4096 + wd1] = kreg1;                            \
            *(f16x8*)&lds[8192 + nb * 4096 + wd0] = vreg0;                     \
            *(f16x8*)&lds[8192 + nb * 4096 + wd1] = vreg1;                     \
            __syncthreads();                                                   \
        }                                                                      \
    } while (0)

#pragma unroll 1
    for (int kt = 0; kt < 30; kt += 2) {
        ATTN_STEP(0, kt, 1);
        ATTN_STEP(1, kt + 1, 1);
    }
    ATTN_STEP(0, 30, 1);
    ATTN_STEP(1, 31, 0);
#undef ATTN_STEP
#undef ATTN_SUB

    // epilogue: combine l halves, normalize, write ctx
    float lr = lrv + __shfl_xor(lrv, 32);
    float inv = 1.f / lr;
#pragma unroll
    for (int r = 0; r < 16; ++r) {
        int crow = (r & 3) + 8 * (r >> 2);
        float ir = __shfl(inv, crow + 4 * hh);
        int s = qbase + crow + 4 * hh;
        f16* dst = ctx + ((size_t)b * S_ + s) * E_ + h * DH_ + q32;
        dst[0]  = (f16)(accO0[r] * ir);
        dst[32] = (f16)(accO1[r] * ir);
    }
}

// ---------------------------------------------------------------------------
// Kernel 3: out = ctx @ Wo^T + bo (unchanged from round 7).
// ---------------------------------------------------------------------------
__global__ __launch_bounds__(256) void gemm_out(
    const f16* __restrict__ A,
    const f16* __restrict__ Bw,
    const float* __restrict__ bo,
    float* __restrict__ out)
{
    __shared__ __align__(16) f16 Al[2][128 * 64];
    __shared__ __align__(16) f16 Bl[2][64 * 64];

    int tid = threadIdx.x, lane = tid & 63, wv = tid >> 6;
    int bid = blockIdx.x;
    int sb = (bid & 7) * 64 + (bid >> 3);
    int mbase = (sb & 31) * 128, nbase = (sb >> 5) * 64;
    int c = lane & 15, g = lane >> 4;
    int wr = wv >> 1, wc = wv & 1;
    int swz = (c & 7) << 3;

    int adst[4]; const f16* asrc[4];
#pragma unroll
    for (int i = 0; i < 4; ++i) {
        int slot = tid + i * 256;
        int row = slot >> 3, cc = slot & 7;
        adst[i] = row * 64 + ((cc * 8) ^ ((row & 7) << 3));
        asrc[i] = A + (size_t)(mbase + row) * 1024 + cc * 8;
    }
    int bdst[2]; const f16* bsrc[2];
#pragma unroll
    for (int i = 0; i < 2; ++i) {
        int slot = tid + i * 256;
        int row = slot >> 3, cc = slot & 7;
        bdst[i] = row * 64 + ((cc * 8) ^ ((row & 7) << 3));
        bsrc[i] = Bw + (size_t)(nbase + row) * 1024 + cc * 8;
    }

    f32x4 acc[4][2] = {};
    f16x8 areg[4], breg[2];

#pragma unroll
    for (int i = 0; i < 4; ++i) areg[i] = *(const f16x8*)asrc[i];
#pragma unroll
    for (int i = 0; i < 2; ++i) breg[i] = *(const f16x8*)bsrc[i];
#pragma unroll
    for (int i = 0; i < 4; ++i) *(f16x8*)&Al[0][adst[i]] = areg[i];
#pragma unroll
    for (int i = 0; i < 2; ++i) *(f16x8*)&Bl[0][bdst[i]] = breg[i];
    __syncthreads();

#define GEMM_STEP(CUR, T, STAGE)                                               \
    do {                                                                       \
        if (STAGE) {                                                           \
            _Pragma("unroll")                                                  \
            for (int i = 0; i < 4; ++i)                                        \
                areg[i] = *(const f16x8*)(asrc[i] + ((T) + 1) * 64);           \
            _Pragma("unroll")                                                  \
            for (int i = 0; i < 2; ++i)                                        \
                breg[i] = *(const f16x8*)(bsrc[i] + ((T) + 1) * 64);           \
        }                                                                      \
        __builtin_amdgcn_s_setprio(1);                                         \
        _Pragma("unroll")                                                      \
        for (int kk = 0; kk < 2; ++kk) {                                       \
            f16x8 af[4], bf[2];                                                \
            _Pragma("unroll")                                                  \
            for (int mi = 0; mi < 4; ++mi)                                     \
                af[mi] = *(const f16x8*)&Al[CUR][(wr * 64 + mi * 16 + c) * 64  \
                                               + ((32 * kk + 8 * g) ^ swz)];   \
            _Pragma("unroll")                                                  \
            for (int ni = 0; ni < 2; ++ni)                                     \
                bf[ni] = *(const f16x8*)&Bl[CUR][(wc * 32 + ni * 16 + c) * 64  \
                                               + ((32 * kk + 8 * g) ^ swz)];   \
            _Pragma("unroll")                                                  \
            for (int mi = 0; mi < 4; ++mi)                                     \
                _Pragma("unroll")                                              \
                for (int ni = 0; ni < 2; ++ni)                                 \
                    acc[mi][ni] = mfma16(af[mi], bf[ni], acc[mi][ni]);         \
        }                                                                      \
        __builtin_amdgcn_s_setprio(0);                                         \
        if (STAGE) {                                                           \
            int nb = (CUR) ^ 1;                                                \
            _Pragma("unroll")                                                  \
            for (int i = 0; i < 4; ++i) *(f16x8*)&Al[nb][adst[i]] = areg[i];   \
            _Pragma("unroll")                                                  \
            for (int i = 0; i < 2; ++i) *(f16x8*)&Bl[nb][bdst[i]] = breg[i];   \
            __syncthreads();                                                   \
        }                                                                      \
    } while (0)

#pragma unroll 1
    for (int ks = 0; ks < 14; ks += 2) {
        GEMM_STEP(0, ks, 1);
        GEMM_STEP(1, ks + 1, 1);
    }
    GEMM_STEP(0, 14, 1);
    GEMM_STEP(1, 15, 0);
#undef GEMM_STEP

#pragma unroll
    for (int ni = 0; ni < 2; ++ni) {
        float bias = bo[nbase + wc * 32 + ni * 16 + c];
#pragma unroll
        for (int mi = 0; mi < 4; ++mi)
#pragma unroll
            for (int j = 0; j < 4; ++j) {
                int m = mbase + wr * 64 + mi * 16 + g * 4 + j;
                out[(size_t)m * 1024 + nbase + wc * 32 + ni * 16 + c] =
                    acc[mi][ni][j] + bias;
            }
    }
}

extern "C" void kernel_launch(void* const* d_in, const int* in_sizes, int n_in,
                              void* d_out, int out_size, void* d_ws, size_t ws_size,
                              hipStream_t stream)
{
    const float* k_in = (const float*)d_in[0];
    const float* q_in = (const float*)d_in[1];
    const float* v_in = (const float*)d_in[2];
    const float* Wq   = (const float*)d_in[3];
    const float* Wk   = (const float*)d_in[4];
    const float* Wv   = (const float*)d_in[5];
    const float* Wo   = (const float*)d_in[6];
    const float* bo   = (const float*)d_in[7];
    float* out = (float*)d_out;

    char* ws = (char*)d_ws;
    f16* Qg  = (f16*)(ws);
    f16* Kg  = (f16*)(ws + (8u << 20));
    f16* Vt  = (f16*)(ws + (16u << 20));
    f16* ctx = (f16*)(ws + (24u << 20));
    f16* WoH = (f16*)(ws + (32u << 20));

    proj_cvt_kernel<<<dim3(4096), dim3(256), 0, stream>>>(
        q_in, k_in, v_in, Wq, Wk, Wv, Wo, Qg, Kg, Vt, WoH);
    attn_kernel<<<dim3(512), dim3(256), 0, stream>>>(Qg, Kg, Vt, ctx);
    gemm_out<<<dim3(512), dim3(256), 0, stream>>>(ctx, WoH, bo, out);
}

// Round 10
// 117.883 us; speedup vs baseline: 1.0219x; 1.0064x over previous
//
#include <hip/hip_runtime.h>
#include <hip/hip_fp16.h>

typedef _Float16 f16;
typedef __fp16 hf16x2 __attribute__((ext_vector_type(2)));
typedef _Float16 f16x8 __attribute__((ext_vector_type(8)));
typedef _Float16 f16x4v __attribute__((ext_vector_type(4)));
typedef float f32x4 __attribute__((ext_vector_type(4)));
typedef float f32x16 __attribute__((ext_vector_type(16)));

#define B_ 2
#define S_ 2048
#define E_ 1024
#define H_ 16
#define DH_ 64

__device__ __forceinline__ f32x4 mfma16(f16x8 a, f16x8 b, f32x4 c) {
    return __builtin_amdgcn_mfma_f32_16x16x32_f16(a, b, c, 0, 0, 0);
}
__device__ __forceinline__ f32x16 mfma32(f16x8 a, f16x8 b, f32x16 c) {
    return __builtin_amdgcn_mfma_f32_32x32x16_f16(a, b, c, 0, 0, 0);
}

__device__ __forceinline__ f16x8 cvt8(const float* p) {
    float4 v0 = *(const float4*)p;
    float4 v1 = *(const float4*)(p + 4);
    f16x8 r;
    r[0] = (f16)v0.x; r[1] = (f16)v0.y; r[2] = (f16)v0.z; r[3] = (f16)v0.w;
    r[4] = (f16)v1.x; r[5] = (f16)v1.y; r[6] = (f16)v1.z; r[7] = (f16)v1.w;
    return r;
}

// ---------------------------------------------------------------------------
// Kernel 1: per-head projections + Wo cvt. Q/K epilogue via per-wave LDS
// transpose slab -> 2 coalesced dwordx4 stores per wave.
// ---------------------------------------------------------------------------
__global__ __launch_bounds__(256) void proj_cvt_kernel(
    const float* __restrict__ q_in, const float* __restrict__ k_in,
    const float* __restrict__ v_in,
    const float* __restrict__ Wq, const float* __restrict__ Wk,
    const float* __restrict__ Wv, const float* __restrict__ Wo,
    f16* __restrict__ Qg, f16* __restrict__ Kg, f16* __restrict__ Vt,
    f16* __restrict__ WoH)
{
    __shared__ __align__(16) f16 tr[4][16 * 72];   // per-wave transpose slab

    int tid = threadIdx.x;
    int bx = blockIdx.x;
    if (bx >= 3072) {
        int i = (bx - 3072) * 256 + tid;
        float4 v = *(const float4*)(Wo + (size_t)i * 4);
        f16x4v o;
        o[0] = (f16)v.x; o[1] = (f16)v.y; o[2] = (f16)v.z; o[3] = (f16)v.w;
        *(f16x4v*)(WoH + (size_t)i * 4) = o;
        return;
    }

    int lane = tid & 63, wv = tid >> 6;
    int wid = bx * 4 + wv;
    int proj = wid >> 12;
    int r = wid & 4095;
    int bh = r >> 7;
    int stile = r & 127;
    int sbase = stile * 16;
    int c = lane & 15, g = lane >> 4;

    const float* x; const float* W;
    if (proj == 0)      { x = q_in; W = Wq; }
    else if (proj == 1) { x = k_in; W = Wk; }
    else                { x = v_in; W = Wv; }

    {
        int h = bh & 15, b = bh >> 4;
        const float* xrow = x + (((size_t)(b * S_ + sbase + c) * H_ + h) << 6);
        f16x8 a0 = cvt8(xrow + g * 8);
        f16x8 a1 = cvt8(xrow + 32 + g * 8);

        f32x4 acc[4] = {};
#pragma unroll
        for (int nt = 0; nt < 4; ++nt) {
            const float* wrow = W + ((nt * 16 + c) << 6);
            f16x8 b0 = cvt8(wrow + g * 8);
            f16x8 b1 = cvt8(wrow + 32 + g * 8);
            acc[nt] = mfma16(a0, b0, acc[nt]);
            acc[nt] = mfma16(a1, b1, acc[nt]);
        }

        if (proj < 2) {
            f16* out = (proj == 0) ? Qg : Kg;
            f16* T = &tr[wv][0];
#pragma unroll
            for (int nt = 0; nt < 4; ++nt)
#pragma unroll
                for (int j = 0; j < 4; ++j)
                    T[(4 * g + j) * 72 + nt * 16 + c] = (f16)acc[nt][j];
            // wave-local RAW: compiler inserts lgkmcnt wait, no barrier
            int rr = lane >> 3, cc8 = lane & 7;
            f16x8 r0 = *(const f16x8*)&T[rr * 72 + cc8 * 8];
            f16x8 r1 = *(const f16x8*)&T[(8 + rr) * 72 + cc8 * 8];
            *(f16x8*)(out + ((size_t)bh * S_ + sbase + rr) * DH_ + cc8 * 8) = r0;
            *(f16x8*)(out + ((size_t)bh * S_ + sbase + 8 + rr) * DH_ + cc8 * 8) = r1;
        } else {
#pragma unroll
            for (int nt = 0; nt < 4; ++nt) {
                f16x4v pk;
                pk[0] = (f16)acc[nt][0]; pk[1] = (f16)acc[nt][1];
                pk[2] = (f16)acc[nt][2]; pk[3] = (f16)acc[nt][3];
                *(f16x4v*)&Vt[((size_t)bh * DH_ + nt * 16 + c) * S_ + sbase + g * 4] = pk;
            }
        }
    }
}

// ---------------------------------------------------------------------------
// Kernel 2: flash attention, 32x32 MFMA, in-register P, subtile-pipelined.
// 256 thr = 4 waves x 32 q-rows. KVBLK=64, compile-time dbuf, 1 barrier/step.
// QK(sub0)+QK(sub1) issued back-to-back; then SM0->PV0, SM1->PV1.
// P-fragment assembly via shfl_xor+select (verified round-8 form).
// ---------------------------------------------------------------------------
#define C1_ 0.18033688011112042f   // log2(e)/sqrt(64)

__global__ __launch_bounds__(256, 2) void attn_kernel(
    const f16* __restrict__ Qg, const f16* __restrict__ Kg,
    const f16* __restrict__ Vt, f16* __restrict__ ctx)
{
    // [0,8192): K dbuf (two 32x128 f16 tiles), [8192,16384): V dbuf
    __shared__ __align__(16) f16 lds[16384];

    int tid = threadIdx.x, lane = tid & 63, wv = tid >> 6;
    int bid = blockIdx.x;
    int sb = (bid & 7) * 64 + (bid >> 3);    // XCD-contiguous: bh-major
    int bh = sb >> 4, qt = sb & 15;
    int b = bh >> 4, h = bh & 15;
    int qbase = qt * 128 + wv * 32;
    int q32 = lane & 31, hh = lane >> 5;
    bool isLo = (hh == 0);

    const f16* Qh = Qg + (size_t)bh * S_ * DH_;
    const f16* Kh = Kg + (size_t)bh * S_ * DH_;
    const f16* Vh = Vt + (size_t)bh * DH_ * S_;

    int swzr = (q32 & 15) << 3;
    int cr[8];
#pragma unroll
    for (int a = 0; a < 2; ++a)
#pragma unroll
        for (int s = 0; s < 4; ++s)
            cr[4 * a + s] = q32 * 128 + ((a * 64 + 16 * s + 8 * hh) ^ swzr);

    int s0 = tid, s1 = tid + 256;
    int e0 = s0 >> 3, c0 = s0 & 7, e1 = s1 >> 3, c1 = s1 & 7;
    int wd0 = (e0 & 31) * 128 + ((((e0 >> 5) * 64) + c0 * 8) ^ (((e0 & 31) & 15) << 3));
    int wd1 = (e1 & 31) * 128 + ((((e1 >> 5) * 64) + c1 * 8) ^ (((e1 & 31) & 15) << 3));
    const f16* ksp0 = Kh + e0 * 64 + c0 * 8;
    const f16* ksp1 = Kh + e1 * 64 + c1 * 8;
    const f16* vsp0 = Vh + (size_t)e0 * S_ + c0 * 8;
    const f16* vsp1 = Vh + (size_t)e1 * S_ + c1 * 8;

    f16x8 qf[4];
#pragma unroll
    for (int s = 0; s < 4; ++s)
        qf[s] = *(const f16x8*)(Qh + (size_t)(qbase + q32) * DH_ + 16 * s + 8 * hh);

    float m2 = -1e30f, lrv = 0.f;
    f32x16 accO0 = {}, accO1 = {};
    f16x8 kreg0, kreg1, vreg0, vreg1;

    // prologue: stage tile 0
    kreg0 = *(const f16x8*)ksp0; kreg1 = *(const f16x8*)ksp1;
    vreg0 = *(const f16x8*)vsp0; vreg1 = *(const f16x8*)vsp1;
    *(f16x8*)&lds[wd0] = kreg0; *(f16x8*)&lds[wd1] = kreg1;
    *(f16x8*)&lds[8192 + wd0] = vreg0; *(f16x8*)&lds[8192 + wd1] = vreg1;
    __syncthreads();

#define SMPV(CUR, SUBI, ACCS, RMAX)                                            \
    do {                                                                       \
        if (!__all(fmaf(RMAX, C1_, -m2) <= 8.f)) {                             \
            float mn = fmaxf(m2, (RMAX) * C1_);                                \
            float al = exp2f(m2 - mn);                                         \
            m2 = mn; lrv *= al;                                                \
            _Pragma("unroll")                                                  \
            for (int r = 0; r < 16; ++r) {                                     \
                float aj = __shfl(al, ((r & 3) + 8 * (r >> 2)) + 4 * hh);      \
                accO0[r] *= aj; accO1[r] *= aj;                                \
            }                                                                  \
        }                                                                      \
        unsigned w[8];                                                         \
        _Pragma("unroll")                                                      \
        for (int j = 0; j < 8; ++j) {                                          \
            float ea = exp2f(fmaf(ACCS[2 * j], C1_, -m2));                     \
            float eb = exp2f(fmaf(ACCS[2 * j + 1], C1_, -m2));                 \
            lrv += ea + eb;                                                    \
            hf16x2 pk = __builtin_amdgcn_cvt_pkrtz(ea, eb);                    \
            w[j] = __builtin_bit_cast(unsigned, pk);                           \
        }                                                                      \
        _Pragma("unroll")                                                      \
        for (int s2 = 0; s2 < 2; ++s2) {                                       \
            unsigned b0 = w[4 * s2 + 0], b1 = w[4 * s2 + 1];                   \
            unsigned b2 = w[4 * s2 + 2], b3 = w[4 * s2 + 3];                   \
            unsigned x0 = (unsigned)__shfl_xor((int)b0, 32);                   \
            unsigned x1 = (unsigned)__shfl_xor((int)b1, 32);                   \
            unsigned x2 = (unsigned)__shfl_xor((int)b2, 32);                   \
            unsigned x3 = (unsigned)__shfl_xor((int)b3, 32);                   \
            uint4 au;                                                          \
            au.x = isLo ? b0 : x2;                                             \
            au.y = isLo ? b1 : x3;                                             \
            au.z = isLo ? x0 : b2;                                             \
            au.w = isLo ? x1 : b3;                                             \
            f16x8 pa = __builtin_bit_cast(f16x8, au);                          \
            __builtin_amdgcn_s_setprio(1);                                     \
            {                                                                  \
                f16x8 vb = *(const f16x8*)&lds[8192 + (CUR) * 4096             \
                                               + cr[(SUBI) * 2 + s2]];         \
                accO0 = mfma32(pa, vb, accO0);                                 \
            }                                                                  \
            {                                                                  \
                f16x8 vb = *(const f16x8*)&lds[8192 + (CUR) * 4096             \
                                               + cr[4 + (SUBI) * 2 + s2]];     \
                accO1 = mfma32(pa, vb, accO1);                                 \
            }                                                                  \
            __builtin_amdgcn_s_setprio(0);                                     \
        }                                                                      \
    } while (0)

#define ATTN_STEP(CUR, T, STAGE)                                               \
    do {                                                                       \
        if (STAGE) {                                                           \
            kreg0 = *(const f16x8*)(ksp0 + ((T) + 1) * 4096);                  \
            kreg1 = *(const f16x8*)(ksp1 + ((T) + 1) * 4096);                  \
            vreg0 = *(const f16x8*)(vsp0 + ((T) + 1) * 64);                    \
            vreg1 = *(const f16x8*)(vsp1 + ((T) + 1) * 64);                    \
        }                                                                      \
        f32x16 accS0 = {}, accS1 = {};                                         \
        __builtin_amdgcn_s_setprio(1);                                         \
        _Pragma("unroll")                                                      \
        for (int s = 0; s < 4; ++s) {                                          \
            f16x8 kf = *(const f16x8*)&lds[(CUR) * 4096 + cr[s]];              \
            accS0 = mfma32(kf, qf[s], accS0);                                  \
        }                                                                      \
        _Pragma("unroll")                                                      \
        for (int s = 0; s < 4; ++s) {                                          \
            f16x8 kf = *(const f16x8*)&lds[(CUR) * 4096 + cr[4 + s]];          \
            accS1 = mfma32(kf, qf[s], accS1);                                  \
        }                                                                      \
        __builtin_amdgcn_s_setprio(0);                                         \
        float rmax0 = accS0[0], rmax1 = accS1[0];                              \
        _Pragma("unroll")                                                      \
        for (int r = 1; r < 16; ++r) {                                         \
            rmax0 = fmaxf(rmax0, accS0[r]);                                    \
            rmax1 = fmaxf(rmax1, accS1[r]);                                    \
        }                                                                      \
        rmax0 = fmaxf(rmax0, __shfl_xor(rmax0, 32));                           \
        rmax1 = fmaxf(rmax1, __shfl_xor(rmax1, 32));                           \
        SMPV(CUR, 0, accS0, rmax0);                                            \
        SMPV(CUR, 1, accS1, rmax1);                                            \
        if (STAGE) {                                                           \
            int nb = (CUR) ^ 1;                                                \
            *(f16x8*)&lds[nb * 4096 + wd0] = kreg0;                            \
            *(f16x8*)&lds[nb * 4096 + wd1] = kreg1;                            \
            *(f16x8*)&lds[8192 + nb * 4096 + wd0] = vreg0;                     \
            *(f16x8*)&lds[8192 + nb * 4096 + wd1] = vreg1;                     \
            __syncthreads();                                                   \
        }                                                                      \
    } while (0)

#pragma unroll 1
    for (int kt = 0; kt < 30; kt += 2) {
        ATTN_STEP(0, kt, 1);
        ATTN_STEP(1, kt + 1, 1);
    }
    ATTN_STEP(0, 30, 1);
    ATTN_STEP(1, 31, 0);
#undef ATTN_STEP
#undef SMPV

    // epilogue: combine l halves, normalize, write ctx
    float lr = lrv + __shfl_xor(lrv, 32);
    float inv = 1.f / lr;
#pragma unroll
    for (int r = 0; r < 16; ++r) {
        int crow = (r & 3) + 8 * (r >> 2);
        float ir = __shfl(inv, crow + 4 * hh);
        int s = qbase + crow + 4 * hh;
        f16* dst = ctx + ((size_t)b * S_ + s) * E_ + h * DH_ + q32;
        dst[0]  = (f16)(accO0[r] * ir);
        dst[32] = (f16)(accO1[r] * ir);
    }
}

// ---------------------------------------------------------------------------
// Kernel 3: out = ctx @ Wo^T + bo (unchanged).
// ---------------------------------------------------------------------------
__global__ __launch_bounds__(256) void gemm_out(
    const f16* __restrict__ A,
    const f16* __restrict__ Bw,
    const float* __restrict__ bo,
    float* __restrict__ out)
{
    __shared__ __align__(16) f16 Al[2][128 * 64];
    __shared__ __align__(16) f16 Bl[2][64 * 64];

    int tid = threadIdx.x, lane = tid & 63, wv = tid >> 6;
    int bid = blockIdx.x;
    int sb = (bid & 7) * 64 + (bid >> 3);
    int mbase = (sb & 31) * 128, nbase = (sb >> 5) * 64;
    int c = lane & 15, g = lane >> 4;
    int wr = wv >> 1, wc = wv & 1;
    int swz = (c & 7) << 3;

    int adst[4]; const f16* asrc[4];
#pragma unroll
    for (int i = 0; i < 4; ++i) {
        int slot = tid + i * 256;
        int row = slot >> 3, cc = slot & 7;
        adst[i] = row * 64 + ((cc * 8) ^ ((row & 7) << 3));
        asrc[i] = A + (size_t)(mbase + row) * 1024 + cc * 8;
    }
    int bdst[2]; const f16* bsrc[2];
#pragma unroll
    for (int i = 0; i < 2; ++i) {
        int slot = tid + i * 256;
        int row = slot >> 3, cc = slot & 7;
        bdst[i] = row * 64 + ((cc * 8) ^ ((row & 7) << 3));
        bsrc[i] = Bw + (size_t)(nbase + row) * 1024 + cc * 8;
    }

    f32x4 acc[4][2] = {};
    f16x8 areg[4], breg[2];

#pragma unroll
    for (int i = 0; i < 4; ++i) areg[i] = *(const f16x8*)asrc[i];
#pragma unroll
    for (int i = 0; i < 2; ++i) breg[i] = *(const f16x8*)bsrc[i];
#pragma unroll
    for (int i = 0; i < 4; ++i) *(f16x8*)&Al[0][adst[i]] = areg[i];
#pragma unroll
    for (int i = 0; i < 2; ++i) *(f16x8*)&Bl[0][bdst[i]] = breg[i];
    __syncthreads();

#define GEMM_STEP(CUR, T, STAGE)                                               \
    do {                                                                       \
        if (STAGE) {                                                           \
            _Pragma("unroll")                                                  \
            for (int i = 0; i < 4; ++i)                                        \
                areg[i] = *(const f16x8*)(asrc[i] + ((T) + 1) * 64);           \
            _Pragma("unroll")                                                  \
            for (int i = 0; i < 2; ++i)                                        \
                breg[i] = *(const f16x8*)(bsrc[i] + ((T) + 1) * 64);           \
        }                                                                      \
        __builtin_amdgcn_s_setprio(1);                                         \
        _Pragma("unroll")                                                      \
        for (int kk = 0; kk < 2; ++kk) {                                       \
            f16x8 af[4], bf[2];                                                \
            _Pragma("unroll")                                                  \
            for (int mi = 0; mi < 4; ++mi)                                     \
                af[mi] = *(const f16x8*)&Al[CUR][(wr * 64 + mi * 16 + c) * 64  \
                                               + ((32 * kk + 8 * g) ^ swz)];   \
            _Pragma("unroll")                                                  \
            for (int ni = 0; ni < 2; ++ni)                                     \
                bf[ni] = *(const f16x8*)&Bl[CUR][(wc * 32 + ni * 16 + c) * 64  \
                                               + ((32 * kk + 8 * g) ^ swz)];   \
            _Pragma("unroll")                                                  \
            for (int mi = 0; mi < 4; ++mi)                                     \
                _Pragma("unroll")                                              \
                for (int ni = 0; ni < 2; ++ni)                                 \
                    acc[mi][ni] = mfma16(af[mi], bf[ni], acc[mi][ni]);         \
        }                                                                      \
        __builtin_amdgcn_s_setprio(0);                                         \
        if (STAGE) {                                                           \
            int nb = (CUR) ^ 1;                                                \
            _Pragma("unroll")                                                  \
            for (int i = 0; i < 4; ++i) *(f16x8*)&Al[nb][adst[i]] = areg[i];   \
            _Pragma("unroll")                                                  \
            for (int i = 0; i < 2; ++i) *(f16x8*)&Bl[nb][bdst[i]] = breg[i];   \
            __syncthreads();                                                   \
        }                                                                      \
    } while (0)

#pragma unroll 1
    for (int ks = 0; ks < 14; ks += 2) {
        GEMM_STEP(0, ks, 1);
        GEMM_STEP(1, ks + 1, 1);
    }
    GEMM_STEP(0, 14, 1);
    GEMM_STEP(1, 15, 0);
#undef GEMM_STEP

#pragma unroll
    for (int ni = 0; ni < 2; ++ni) {
        float bias = bo[nbase + wc * 32 + ni * 16 + c];
#pragma unroll
        for (int mi = 0; mi < 4; ++mi)
#pragma unroll
            for (int j = 0; j < 4; ++j) {
                int m = mbase + wr * 64 + mi * 16 + g * 4 + j;
                out[(size_t)m * 1024 + nbase + wc * 32 + ni * 16 + c] =
                    acc[mi][ni][j] + bias;
            }
    }
}

extern "C" void kernel_launch(void* const* d_in, const int* in_sizes, int n_in,
                              void* d_out, int out_size, void* d_ws, size_t ws_size,
                              hipStream_t stream)
{
    const float* k_in = (const float*)d_in[0];
    const float* q_in = (const float*)d_in[1];
    const float* v_in = (const float*)d_in[2];
    const float* Wq   = (const float*)d_in[3];
    const float* Wk   = (const float*)d_in[4];
    const float* Wv   = (const float*)d_in[5];
    const float* Wo   = (const float*)d_in[6];
    const float* bo   = (const float*)d_in[7];
    float* out = (float*)d_out;

    char* ws = (char*)d_ws;
    f16* Qg  = (f16*)(ws);
    f16* Kg  = (f16*)(ws + (8u << 20));
    f16* Vt  = (f16*)(ws + (16u << 20));
    f16* ctx = (f16*)(ws + (24u << 20));
    f16* WoH = (f16*)(ws + (32u << 20));

    proj_cvt_kernel<<<dim3(4096), dim3(256), 0, stream>>>(
        q_in, k_in, v_in, Wq, Wk, Wv, Wo, Qg, Kg, Vt, WoH);
    attn_kernel<<<dim3(512), dim3(256), 0, stream>>>(Qg, Kg, Vt, ctx);
    gemm_out<<<dim3(512), dim3(256), 0, stream>>>(ctx, WoH, bo, out);
}